// Round 6
// baseline (664.250 us; speedup 1.0000x reference)
//
#include <hip/hip_runtime.h>
#include <hip/hip_bf16.h>
#include <cstdint>

#define N_NODES_C 100000
#define IN_FEAT 512
#define HIDDEN 128
#define N_CLASSES 7
#define T2_STRIDE 8

using f16x8 = __attribute__((ext_vector_type(8))) _Float16;
using f16x2 = __attribute__((ext_vector_type(2))) _Float16;
using f32x4 = __attribute__((ext_vector_type(4))) float;

// ---------------------------------------------------------------- utilities
__global__ void k_zero_int(int* __restrict__ p, int n) {
    int i = blockIdx.x * blockDim.x + threadIdx.x;
    if (i < n) p[i] = 0;
}

// count[v] = number of edges with dst == v
__global__ void k_count(const int* __restrict__ dst, int* __restrict__ count, int E) {
    int i = blockIdx.x * blockDim.x + threadIdx.x;
    if (i < E) atomicAdd(&count[dst[i]], 1);
}

// partial[b] = sum of count[b*256 .. b*256+255]
__global__ __launch_bounds__(256) void k_partsum(const int* __restrict__ count,
                                                 int* __restrict__ partial, int N) {
    int i = blockIdx.x * 256 + threadIdx.x;
    int c = (i < N) ? count[i] : 0;
    #pragma unroll
    for (int off = 32; off >= 1; off >>= 1) c += __shfl_xor(c, off);
    __shared__ int ws[4];
    if ((threadIdx.x & 63) == 0) ws[threadIdx.x >> 6] = c;
    __syncthreads();
    if (threadIdx.x == 0) partial[blockIdx.x] = ws[0] + ws[1] + ws[2] + ws[3];
}

// single small block: exclusive scan of partial[NB] -> partoff; rowp[N] = total
__global__ __launch_bounds__(512) void k_scan_part(const int* __restrict__ partial,
                                                   int* __restrict__ partoff,
                                                   int* __restrict__ rowp, int NB, int N) {
    __shared__ int s[512];
    int t = threadIdx.x;
    int v = (t < NB) ? partial[t] : 0;
    s[t] = v;
    __syncthreads();
    for (int off = 1; off < 512; off <<= 1) {
        int u = (t >= off) ? s[t - off] : 0;
        __syncthreads();
        s[t] += u;
        __syncthreads();
    }
    if (t < NB) partoff[t] = s[t] - v;
    if (t == 511) rowp[N] = s[511];
}

// coalesced block-level scan: rowp/cursor/dinv
__global__ __launch_bounds__(256) void k_scan_final(const int* __restrict__ count,
                                                    const int* __restrict__ partoff,
                                                    int* __restrict__ rowp,
                                                    int* __restrict__ cursor,
                                                    float* __restrict__ dinv, int N) {
    __shared__ int wsum[4];
    int i = blockIdx.x * 256 + threadIdx.x;
    int lane = threadIdx.x & 63, w = threadIdx.x >> 6;
    int c = (i < N) ? count[i] : 0;
    int x = c;
    #pragma unroll
    for (int off = 1; off < 64; off <<= 1) {
        int v = __shfl_up(x, off);
        if (lane >= off) x += v;
    }
    if (lane == 63) wsum[w] = x;
    __syncthreads();
    int woff = 0;
    #pragma unroll
    for (int k = 0; k < 4; ++k)
        if (k < w) woff += wsum[k];
    int excl = partoff[blockIdx.x] + woff + x - c;
    if (i < N) {
        rowp[i] = excl;
        cursor[i] = excl;
        dinv[i] = rsqrtf((float)(c + 1));  // +1 self loop
    }
}

// scatter edges into CSR (grouped by dst, storing src)
__global__ void k_fill(const int* __restrict__ src, const int* __restrict__ dst,
                       int* __restrict__ cursor, int* __restrict__ csr, int E) {
    int i = blockIdx.x * blockDim.x + threadIdx.x;
    if (i < E) {
        int pos = atomicAdd(&cursor[dst[i]], 1);
        csr[pos] = src[i];
    }
}

// ---------------------------------------------------------------- W1 prep
// W1 [512][128] fp32 -> W1T [128][512] f16
__global__ __launch_bounds__(256) void k_prep_w1(const float* __restrict__ W1,
                                                 _Float16* __restrict__ W1T) {
    __shared__ _Float16 tile[16][128];
    const int k0 = blockIdx.x * 16;
    const int t = threadIdx.x;
    #pragma unroll
    for (int i = 0; i < 8; ++i) {
        int idx = i * 256 + t;
        int k = idx >> 7, n = idx & 127;
        tile[k][n] = (_Float16)W1[(size_t)(k0 + k) * HIDDEN + n];
    }
    __syncthreads();
    int n = t >> 1, kh = (t & 1) * 8;
    _Float16 tmp[8];
    #pragma unroll
    for (int i = 0; i < 8; ++i) tmp[i] = tile[kh + i][n];
    *(uint4*)&W1T[(size_t)n * IN_FEAT + k0 + kh] = *(const uint4*)tmp;
}

// ---------------------------------------------------------------- GEMM1 (f16 MFMA)
// t1h[M][128] (f16) = (x @ W1) * dinv[row].
// 16 rows per wave, 64 rows per block -> 1563 blocks (~6 blocks/CU) for TLP.
__global__ __launch_bounds__(256) void k_gemm1(const float* __restrict__ A,
                                               const _Float16* __restrict__ BT,
                                               const float* __restrict__ dinv,
                                               _Float16* __restrict__ t1h, int M) {
    const int wid = threadIdx.x >> 6;
    const int lane = threadIdx.x & 63;
    const int row0 = blockIdx.x * 64 + wid * 16;
    const int r = lane & 15;        // row/col within fragment
    const int kb = lane >> 4;       // k-block 0..3

    f32x4 acc[8];
    #pragma unroll
    for (int j = 0; j < 8; ++j) acc[j] = (f32x4){0.f, 0.f, 0.f, 0.f};

    const int ra = row0 + r;
    const float* arow = &A[(size_t)ra * IN_FEAT];
    const bool avalid = (ra < M);

    for (int ks = 0; ks < IN_FEAT / 32; ++ks) {
        const int kofs = ks * 32 + kb * 8;
        // A fragment: row row0 + r, 8 contiguous k (fp32 -> f16)
        float4 v0 = make_float4(0.f, 0.f, 0.f, 0.f), v1 = v0;
        if (avalid) {
            v0 = *(const float4*)(arow + kofs);
            v1 = *(const float4*)(arow + kofs + 4);
        }
        f16x8 a;
        a[0] = (_Float16)v0.x; a[1] = (_Float16)v0.y;
        a[2] = (_Float16)v0.z; a[3] = (_Float16)v0.w;
        a[4] = (_Float16)v1.x; a[5] = (_Float16)v1.y;
        a[6] = (_Float16)v1.z; a[7] = (_Float16)v1.w;
        // B fragments: col j*16 + r, 8 contiguous k (f16, L2-resident)
        #pragma unroll
        for (int j = 0; j < 8; ++j) {
            f16x8 b = *(const f16x8*)&BT[(size_t)(j * 16 + r) * IN_FEAT + kofs];
            acc[j] = __builtin_amdgcn_mfma_f32_16x16x32_f16(a, b, acc[j], 0, 0, 0);
        }
    }

    // C/D layout: col = lane&15, row = (lane>>4)*4 + i
    #pragma unroll
    for (int i = 0; i < 4; ++i) {
        int rr = row0 + kb * 4 + i;
        if (rr < M) {
            float dd = dinv[rr];
            #pragma unroll
            for (int j = 0; j < 8; ++j)
                t1h[(size_t)rr * HIDDEN + j * 16 + r] = (_Float16)(acc[j][i] * dd);
        }
    }
}

// ---------------------------------------------------------------- Agg1 + GEMM2 fused
// h = relu(dinv[d]*(sum t1h[src] + t1h[d]) + b1);  t2s[d] = (h @ W2) * dinv[d]
// one wave per node; lane holds 2 of 128 features; 8-deep edge unroll for MLP
__global__ __launch_bounds__(256) void k_agg1(const _Float16* __restrict__ t1h,
                                              const int* __restrict__ csr,
                                              const int* __restrict__ rowp,
                                              const float* __restrict__ dinv,
                                              const float* __restrict__ b1,
                                              const float* __restrict__ W2,
                                              float* __restrict__ t2s, int N) {
    const int node = blockIdx.x * 4 + (threadIdx.x >> 6);
    if (node >= N) return;
    const int lane = threadIdx.x & 63;
    const int beg = rowp[node], end = rowp[node + 1];
    float ax = 0.f, ay = 0.f;
    int e = beg;
    for (; e + 8 <= end; e += 8) {
        int s0 = csr[e + 0], s1 = csr[e + 1], s2 = csr[e + 2], s3 = csr[e + 3];
        int s4 = csr[e + 4], s5 = csr[e + 5], s6 = csr[e + 6], s7 = csr[e + 7];
        f16x2 v0 = *(const f16x2*)&t1h[(size_t)s0 * HIDDEN + lane * 2];
        f16x2 v1 = *(const f16x2*)&t1h[(size_t)s1 * HIDDEN + lane * 2];
        f16x2 v2 = *(const f16x2*)&t1h[(size_t)s2 * HIDDEN + lane * 2];
        f16x2 v3 = *(const f16x2*)&t1h[(size_t)s3 * HIDDEN + lane * 2];
        f16x2 v4 = *(const f16x2*)&t1h[(size_t)s4 * HIDDEN + lane * 2];
        f16x2 v5 = *(const f16x2*)&t1h[(size_t)s5 * HIDDEN + lane * 2];
        f16x2 v6 = *(const f16x2*)&t1h[(size_t)s6 * HIDDEN + lane * 2];
        f16x2 v7 = *(const f16x2*)&t1h[(size_t)s7 * HIDDEN + lane * 2];
        ax += (float)v0.x + (float)v1.x + (float)v2.x + (float)v3.x
            + (float)v4.x + (float)v5.x + (float)v6.x + (float)v7.x;
        ay += (float)v0.y + (float)v1.y + (float)v2.y + (float)v3.y
            + (float)v4.y + (float)v5.y + (float)v6.y + (float)v7.y;
    }
    for (; e < end; ++e) {
        int s = csr[e];
        f16x2 v = *(const f16x2*)&t1h[(size_t)s * HIDDEN + lane * 2];
        ax += (float)v.x;
        ay += (float)v.y;
    }
    const float dd = dinv[node];
    f16x2 self = *(const f16x2*)&t1h[(size_t)node * HIDDEN + lane * 2];
    float2 bb = *(const float2*)&b1[lane * 2];
    float hx = fmaxf(dd * (ax + (float)self.x) + bb.x, 0.f);
    float hy = fmaxf(dd * (ay + (float)self.y) + bb.y, 0.f);
    // project to 7 classes: per-lane partial, butterfly reduce over 64 lanes
    float acc[N_CLASSES];
    #pragma unroll
    for (int j = 0; j < N_CLASSES; ++j)
        acc[j] = hx * W2[(2 * lane) * N_CLASSES + j] + hy * W2[(2 * lane + 1) * N_CLASSES + j];
    #pragma unroll
    for (int off = 32; off >= 1; off >>= 1)
        #pragma unroll
        for (int j = 0; j < N_CLASSES; ++j) acc[j] += __shfl_xor(acc[j], off);
    if (lane == 0) {
        float* row = &t2s[(size_t)node * T2_STRIDE];
        *(float4*)row = make_float4(acc[0] * dd, acc[1] * dd, acc[2] * dd, acc[3] * dd);
        *(float4*)(row + 4) = make_float4(acc[4] * dd, acc[5] * dd, acc[6] * dd, 0.f);
    }
}

// ---------------------------------------------------------------- Agg2
// out[d][j] = dinv[d]*(sum t2s[src] + t2s[d]) + b2[j]; 8 lanes per node (j-parallel)
__global__ __launch_bounds__(256) void k_agg2(const float* __restrict__ t2s,
                                              const int* __restrict__ csr,
                                              const int* __restrict__ rowp,
                                              const float* __restrict__ dinv,
                                              const float* __restrict__ b2,
                                              float* __restrict__ out, int N) {
    const int node = blockIdx.x * 32 + (threadIdx.x >> 3);
    const int j = threadIdx.x & 7;
    if (node >= N) return;
    const int beg = rowp[node], end = rowp[node + 1];
    float acc = 0.f;
    int e = beg;
    for (; e + 4 <= end; e += 4) {
        int s0 = csr[e + 0], s1 = csr[e + 1], s2 = csr[e + 2], s3 = csr[e + 3];
        float a0 = t2s[(size_t)s0 * T2_STRIDE + j];
        float a1 = t2s[(size_t)s1 * T2_STRIDE + j];
        float a2 = t2s[(size_t)s2 * T2_STRIDE + j];
        float a3 = t2s[(size_t)s3 * T2_STRIDE + j];
        acc += (a0 + a1) + (a2 + a3);
    }
    for (; e < end; ++e)
        acc += t2s[(size_t)csr[e] * T2_STRIDE + j];
    if (j < N_CLASSES) {
        float dd = dinv[node];
        out[(size_t)node * N_CLASSES + j] =
            dd * (acc + t2s[(size_t)node * T2_STRIDE + j]) + b2[j];
    }
}

// ---------------------------------------------------------------- launch
extern "C" void kernel_launch(void* const* d_in, const int* in_sizes, int n_in,
                              void* d_out, int out_size, void* d_ws, size_t ws_size,
                              hipStream_t stream) {
    const float* x  = (const float*)d_in[0];
    const int*   ei = (const int*)d_in[1];
    const float* W1 = (const float*)d_in[2];
    const float* b1 = (const float*)d_in[3];
    const float* W2 = (const float*)d_in[4];
    const float* b2 = (const float*)d_in[5];
    float* out = (float*)d_out;

    const int N = N_NODES_C;
    const int E = in_sizes[1] / 2;
    const int* src = ei;
    const int* dst = ei + E;
    const int NB = (N + 255) / 256;  // 391 scan blocks

    size_t off = 0;
    auto alloc = [&](size_t bytes) {
        void* p = (char*)d_ws + off;
        off += (bytes + 255) & ~(size_t)255;
        return p;
    };
    int*      count   = (int*)alloc((size_t)N * 4);
    int*      rowp    = (int*)alloc((size_t)(N + 1) * 4);
    int*      cursor  = (int*)alloc((size_t)N * 4);
    int*      csr     = (int*)alloc((size_t)E * 4);
    float*    dinv    = (float*)alloc((size_t)N * 4);
    int*      partial = (int*)alloc((size_t)512 * 4);
    int*      partoff = (int*)alloc((size_t)512 * 4);
    _Float16* W1T     = (_Float16*)alloc((size_t)HIDDEN * IN_FEAT * 2);
    _Float16* t1h     = (_Float16*)alloc((size_t)N * HIDDEN * 2);
    float*    t2s     = (float*)alloc((size_t)N * T2_STRIDE * 4);
    (void)ws_size;

    // degree histogram + coalesced 3-phase scan + CSR fill
    k_zero_int<<<(N + 255) / 256, 256, 0, stream>>>(count, N);
    k_count<<<(E + 255) / 256, 256, 0, stream>>>(dst, count, E);
    k_partsum<<<NB, 256, 0, stream>>>(count, partial, N);
    k_scan_part<<<1, 512, 0, stream>>>(partial, partoff, rowp, NB, N);
    k_scan_final<<<NB, 256, 0, stream>>>(count, partoff, rowp, cursor, dinv, N);
    k_fill<<<(E + 255) / 256, 256, 0, stream>>>(src, dst, cursor, csr, E);
    // W1 -> f16 transposed
    k_prep_w1<<<IN_FEAT / 16, 256, 0, stream>>>(W1, W1T);
    // t1h = (x @ W1) * dinv   (f16), 64 rows/block
    k_gemm1<<<(N + 63) / 64, 256, 0, stream>>>(x, W1T, dinv, t1h, N);
    // fused agg1 + relu + gemm2 -> t2s (padded stride 8)
    k_agg1<<<(N + 3) / 4, 256, 0, stream>>>(t1h, csr, rowp, dinv, b1, W2, t2s, N);
    // out = agg(t2s) + b2
    k_agg2<<<(N + 31) / 32, 256, 0, stream>>>(t2s, csr, rowp, dinv, b2, out, N);
}